// Round 20
// baseline (1985.980 us; speedup 1.0000x reference)
//
#include <hip/hip_runtime.h>
#include <hip/hip_bf16.h>

#define HIDDEN 256
#define BATCH  64
#define SEQ    2048

// ---------------------------------------------------------------------------
// Phase 1: x_pre[row,h] = bias[h] + sum_d embed[x[row],d] * Wx[h,d]
// xpre is LDS-INSTRUCTION-bound (broadcast e-reads through the CU-shared
// LDS pipe: 4096 instrs/block ~= 786k cyc/CU >> 262k cyc of FMA issue).
// Ratio lever = cols/thread: 4 cols x 8 rows -> each b128 e-read feeds
// 16 FMAs (was 8), halving LDS instrs. R4's 4-col attempt regressed due to
// v2f ext-vector acc arrays (scratch, rule #20); this version uses SCALAR
// float accs (32 VGPR, statically indexed) + plain fmaf. e-staging, W
// streaming pattern (each W row read once per block, L2-hot), and the
// per-column d-summation order are identical to the proven kernel.
// ---------------------------------------------------------------------------
__global__ __launch_bounds__(256, 4)
void xpre_kernel(const int* __restrict__ x,
                 const float* __restrict__ embed,
                 const float* __restrict__ Wx,
                 const float* __restrict__ bias,
                 float* __restrict__ out) {
    const int tid = threadIdx.x;
    const int rg  = tid >> 6;        // row group: rows [8rg, 8rg+8)
    const int j   = tid & 63;        // base col; owns {j, j+64, j+128, j+192}
    const long row0 = (long)blockIdx.x * 32;

    __shared__ int toks[32];
    __shared__ __align__(16) float e[32][HIDDEN];

    if (tid < 32) toks[tid] = x[row0 + tid];
    __syncthreads();

    #pragma unroll
    for (int r = 0; r < 32; ++r) {
        e[r][tid] = embed[(long)toks[r] * HIDDEN + tid];   // coalesced 1KB/row
    }
    __syncthreads();

    const float* wr0 = Wx + (size_t)(j      ) * HIDDEN;
    const float* wr1 = Wx + (size_t)(j +  64) * HIDDEN;
    const float* wr2 = Wx + (size_t)(j + 128) * HIDDEN;
    const float* wr3 = Wx + (size_t)(j + 192) * HIDDEN;

    // scalar accumulators: 4 cols x 8 rows, all statically indexed
    float a0[8], a1[8], a2[8], a3[8];
    const float b0 = bias[j];
    const float b1 = bias[j + 64];
    const float b2 = bias[j + 128];
    const float b3 = bias[j + 192];
    #pragma unroll
    for (int r = 0; r < 8; ++r) { a0[r] = b0; a1[r] = b1; a2[r] = b2; a3[r] = b3; }

    const int rbase = rg << 3;

    #pragma unroll 2
    for (int d0 = 0; d0 < HIDDEN; d0 += 4) {
        const float4 w0 = *(const float4*)(wr0 + d0);
        const float4 w1 = *(const float4*)(wr1 + d0);
        const float4 w2 = *(const float4*)(wr2 + d0);
        const float4 w3 = *(const float4*)(wr3 + d0);
        #pragma unroll
        for (int r = 0; r < 8; ++r) {
            const float4 ev = *(const float4*)&e[rbase + r][d0];  // broadcast
            float t0 = a0[r];
            t0 = fmaf(w0.x, ev.x, t0); t0 = fmaf(w0.y, ev.y, t0);
            t0 = fmaf(w0.z, ev.z, t0); t0 = fmaf(w0.w, ev.w, t0);
            a0[r] = t0;
            float t1 = a1[r];
            t1 = fmaf(w1.x, ev.x, t1); t1 = fmaf(w1.y, ev.y, t1);
            t1 = fmaf(w1.z, ev.z, t1); t1 = fmaf(w1.w, ev.w, t1);
            a1[r] = t1;
            float t2 = a2[r];
            t2 = fmaf(w2.x, ev.x, t2); t2 = fmaf(w2.y, ev.y, t2);
            t2 = fmaf(w2.z, ev.z, t2); t2 = fmaf(w2.w, ev.w, t2);
            a2[r] = t2;
            float t3 = a3[r];
            t3 = fmaf(w3.x, ev.x, t3); t3 = fmaf(w3.y, ev.y, t3);
            t3 = fmaf(w3.z, ev.z, t3); t3 = fmaf(w3.w, ev.w, t3);
            a3[r] = t3;
        }
    }

    #pragma unroll
    for (int r = 0; r < 8; ++r) {
        const size_t orow = (size_t)(row0 + rbase + r) * HIDDEN;
        out[orow + j]       = a0[r];   // 256B contiguous per wave per store
        out[orow + j + 64]  = a1[r];
        out[orow + j + 128] = a2[r];
        out[orow + j + 192] = a3[r];
    }
}

// ---------------------------------------------------------------------------
// Phase 2: whole-loop-in-asm F32 scan — exact R14 configuration (best
// measured: 1120us, reproduced twice). 512 thr (2 waves/EU), thread
// (o=tid&15, pc=tid>>4): 8 cols {pc+32k}, h-slice h[16o..16o+15]; weights
// hand-pinned v[128:255]; counted lgkmcnt(3/2/1/0) MAC interleave; DPP
// merge-reduce; 2-deep x_pre prefetch with vmcnt(2); ds_write before
// global_store; lgkm-only barrier. UNCHANGED.
// ---------------------------------------------------------------------------

#define MAC_ASM(RD) \
  "ds_read_b128 v[48:51], " RD "\n\t" \
  "ds_read_b128 v[52:55], " RD " offset:16\n\t" \
  "ds_read_b128 v[56:59], " RD " offset:32\n\t" \
  "ds_read_b128 v[60:63], " RD " offset:48\n\t" \
  "s_waitcnt lgkmcnt(3)\n\t" \
  "v_pk_mul_f32 v[64:65], v[128:129], v[48:49]\n\t" \
  "v_pk_mul_f32 v[66:67], v[144:145], v[48:49]\n\t" \
  "v_pk_mul_f32 v[68:69], v[160:161], v[48:49]\n\t" \
  "v_pk_mul_f32 v[70:71], v[176:177], v[48:49]\n\t" \
  "v_pk_mul_f32 v[72:73], v[192:193], v[48:49]\n\t" \
  "v_pk_mul_f32 v[74:75], v[208:209], v[48:49]\n\t" \
  "v_pk_mul_f32 v[76:77], v[224:225], v[48:49]\n\t" \
  "v_pk_mul_f32 v[78:79], v[240:241], v[48:49]\n\t" \
  "v_pk_fma_f32 v[64:65], v[130:131], v[50:51], v[64:65]\n\t" \
  "v_pk_fma_f32 v[66:67], v[146:147], v[50:51], v[66:67]\n\t" \
  "v_pk_fma_f32 v[68:69], v[162:163], v[50:51], v[68:69]\n\t" \
  "v_pk_fma_f32 v[70:71], v[178:179], v[50:51], v[70:71]\n\t" \
  "v_pk_fma_f32 v[72:73], v[194:195], v[50:51], v[72:73]\n\t" \
  "v_pk_fma_f32 v[74:75], v[210:211], v[50:51], v[74:75]\n\t" \
  "v_pk_fma_f32 v[76:77], v[226:227], v[50:51], v[76:77]\n\t" \
  "v_pk_fma_f32 v[78:79], v[242:243], v[50:51], v[78:79]\n\t" \
  "s_waitcnt lgkmcnt(2)\n\t" \
  "v_pk_fma_f32 v[64:65], v[132:133], v[52:53], v[64:65]\n\t" \
  "v_pk_fma_f32 v[66:67], v[148:149], v[52:53], v[66:67]\n\t" \
  "v_pk_fma_f32 v[68:69], v[164:165], v[52:53], v[68:69]\n\t" \
  "v_pk_fma_f32 v[70:71], v[180:181], v[52:53], v[70:71]\n\t" \
  "v_pk_fma_f32 v[72:73], v[196:197], v[52:53], v[72:73]\n\t" \
  "v_pk_fma_f32 v[74:75], v[212:213], v[52:53], v[74:75]\n\t" \
  "v_pk_fma_f32 v[76:77], v[228:229], v[52:53], v[76:77]\n\t" \
  "v_pk_fma_f32 v[78:79], v[244:245], v[52:53], v[78:79]\n\t" \
  "v_pk_fma_f32 v[64:65], v[134:135], v[54:55], v[64:65]\n\t" \
  "v_pk_fma_f32 v[66:67], v[150:151], v[54:55], v[66:67]\n\t" \
  "v_pk_fma_f32 v[68:69], v[166:167], v[54:55], v[68:69]\n\t" \
  "v_pk_fma_f32 v[70:71], v[182:183], v[54:55], v[70:71]\n\t" \
  "v_pk_fma_f32 v[72:73], v[198:199], v[54:55], v[72:73]\n\t" \
  "v_pk_fma_f32 v[74:75], v[214:215], v[54:55], v[74:75]\n\t" \
  "v_pk_fma_f32 v[76:77], v[230:231], v[54:55], v[76:77]\n\t" \
  "v_pk_fma_f32 v[78:79], v[246:247], v[54:55], v[78:79]\n\t" \
  "s_waitcnt lgkmcnt(1)\n\t" \
  "v_pk_fma_f32 v[64:65], v[136:137], v[56:57], v[64:65]\n\t" \
  "v_pk_fma_f32 v[66:67], v[152:153], v[56:57], v[66:67]\n\t" \
  "v_pk_fma_f32 v[68:69], v[168:169], v[56:57], v[68:69]\n\t" \
  "v_pk_fma_f32 v[70:71], v[184:185], v[56:57], v[70:71]\n\t" \
  "v_pk_fma_f32 v[72:73], v[200:201], v[56:57], v[72:73]\n\t" \
  "v_pk_fma_f32 v[74:75], v[216:217], v[56:57], v[74:75]\n\t" \
  "v_pk_fma_f32 v[76:77], v[232:233], v[56:57], v[76:77]\n\t" \
  "v_pk_fma_f32 v[78:79], v[248:249], v[56:57], v[78:79]\n\t" \
  "v_pk_fma_f32 v[64:65], v[138:139], v[58:59], v[64:65]\n\t" \
  "v_pk_fma_f32 v[66:67], v[154:155], v[58:59], v[66:67]\n\t" \
  "v_pk_fma_f32 v[68:69], v[170:171], v[58:59], v[68:69]\n\t" \
  "v_pk_fma_f32 v[70:71], v[186:187], v[58:59], v[70:71]\n\t" \
  "v_pk_fma_f32 v[72:73], v[202:203], v[58:59], v[72:73]\n\t" \
  "v_pk_fma_f32 v[74:75], v[218:219], v[58:59], v[74:75]\n\t" \
  "v_pk_fma_f32 v[76:77], v[234:235], v[58:59], v[76:77]\n\t" \
  "v_pk_fma_f32 v[78:79], v[250:251], v[58:59], v[78:79]\n\t" \
  "s_waitcnt lgkmcnt(0)\n\t" \
  "v_pk_fma_f32 v[64:65], v[140:141], v[60:61], v[64:65]\n\t" \
  "v_pk_fma_f32 v[66:67], v[156:157], v[60:61], v[66:67]\n\t" \
  "v_pk_fma_f32 v[68:69], v[172:173], v[60:61], v[68:69]\n\t" \
  "v_pk_fma_f32 v[70:71], v[188:189], v[60:61], v[70:71]\n\t" \
  "v_pk_fma_f32 v[72:73], v[204:205], v[60:61], v[72:73]\n\t" \
  "v_pk_fma_f32 v[74:75], v[220:221], v[60:61], v[74:75]\n\t" \
  "v_pk_fma_f32 v[76:77], v[236:237], v[60:61], v[76:77]\n\t" \
  "v_pk_fma_f32 v[78:79], v[252:253], v[60:61], v[78:79]\n\t" \
  "v_pk_fma_f32 v[64:65], v[142:143], v[62:63], v[64:65]\n\t" \
  "v_pk_fma_f32 v[66:67], v[158:159], v[62:63], v[66:67]\n\t" \
  "v_pk_fma_f32 v[68:69], v[174:175], v[62:63], v[68:69]\n\t" \
  "v_pk_fma_f32 v[70:71], v[190:191], v[62:63], v[70:71]\n\t" \
  "v_pk_fma_f32 v[72:73], v[206:207], v[62:63], v[72:73]\n\t" \
  "v_pk_fma_f32 v[74:75], v[222:223], v[62:63], v[74:75]\n\t" \
  "v_pk_fma_f32 v[76:77], v[238:239], v[62:63], v[76:77]\n\t" \
  "v_pk_fma_f32 v[78:79], v[254:255], v[62:63], v[78:79]\n\t" \
  "v_add_f32 v80, v64, v65\n\t" \
  "v_add_f32 v81, v66, v67\n\t" \
  "v_add_f32 v82, v68, v69\n\t" \
  "v_add_f32 v83, v70, v71\n\t" \
  "v_add_f32 v84, v72, v73\n\t" \
  "v_add_f32 v85, v74, v75\n\t" \
  "v_add_f32 v86, v76, v77\n\t" \
  "v_add_f32 v87, v78, v79\n\t"

// merge-reduce over the 16 o-lanes; lane o ends with total for col pc+32*(o&7)
#define RED_ASM \
  "v_add_f32_dpp v80, v80, v80 row_ror:8 row_mask:0xf bank_mask:0xf\n\t" \
  "v_add_f32_dpp v81, v81, v81 row_ror:8 row_mask:0xf bank_mask:0xf\n\t" \
  "v_add_f32_dpp v82, v82, v82 row_ror:8 row_mask:0xf bank_mask:0xf\n\t" \
  "v_add_f32_dpp v83, v83, v83 row_ror:8 row_mask:0xf bank_mask:0xf\n\t" \
  "v_add_f32_dpp v84, v84, v84 row_ror:8 row_mask:0xf bank_mask:0xf\n\t" \
  "v_add_f32_dpp v85, v85, v85 row_ror:8 row_mask:0xf bank_mask:0xf\n\t" \
  "v_add_f32_dpp v86, v86, v86 row_ror:8 row_mask:0xf bank_mask:0xf\n\t" \
  "v_add_f32_dpp v87, v87, v87 row_ror:8 row_mask:0xf bank_mask:0xf\n\t" \
  "v_cndmask_b32 v88, v81, v80, s[24:25]\n\t" \
  "v_cndmask_b32 v89, v83, v82, s[24:25]\n\t" \
  "v_cndmask_b32 v90, v85, v84, s[24:25]\n\t" \
  "v_cndmask_b32 v91, v87, v86, s[24:25]\n\t" \
  "v_cndmask_b32 v80, v80, v81, s[24:25]\n\t" \
  "v_cndmask_b32 v82, v82, v83, s[24:25]\n\t" \
  "v_cndmask_b32 v84, v84, v85, s[24:25]\n\t" \
  "v_cndmask_b32 v86, v86, v87, s[24:25]\n\t" \
  "v_add_f32_dpp v80, v88, v80 quad_perm:[1,0,3,2] row_mask:0xf bank_mask:0xf\n\t" \
  "v_add_f32_dpp v82, v89, v82 quad_perm:[1,0,3,2] row_mask:0xf bank_mask:0xf\n\t" \
  "v_add_f32_dpp v84, v90, v84 quad_perm:[1,0,3,2] row_mask:0xf bank_mask:0xf\n\t" \
  "v_add_f32_dpp v86, v91, v86 quad_perm:[1,0,3,2] row_mask:0xf bank_mask:0xf\n\t" \
  "v_cndmask_b32 v88, v82, v80, s[26:27]\n\t" \
  "v_cndmask_b32 v89, v86, v84, s[26:27]\n\t" \
  "v_cndmask_b32 v80, v80, v82, s[26:27]\n\t" \
  "v_cndmask_b32 v84, v84, v86, s[26:27]\n\t" \
  "s_nop 1\n\t" \
  "v_add_f32_dpp v80, v88, v80 quad_perm:[2,3,0,1] row_mask:0xf bank_mask:0xf\n\t" \
  "v_add_f32_dpp v84, v89, v84 quad_perm:[2,3,0,1] row_mask:0xf bank_mask:0xf\n\t" \
  "v_cndmask_b32 v88, v84, v80, s[28:29]\n\t" \
  "v_cndmask_b32 v80, v80, v84, s[28:29]\n\t" \
  "s_nop 1\n\t" \
  "v_add_f32_dpp v80, v88, v80 row_ror:4 row_mask:0xf bank_mask:0xf\n\t"

// finish: counted vmcnt wait, xp add, tanh, ds_write FIRST then global store,
// prefetch-reg rotate, pointer advance, lgkmcnt-only barrier.
#define FIN_ASM(WR, XP, MD, MS) \
  "s_waitcnt vmcnt(2)\n\t" \
  "v_add_f32 v99, v80, " XP "\n\t" \
  "v_mul_f32 v93, 0x4038AA3B, v99\n\t" \
  "v_exp_f32 v94, v93\n\t" \
  "s_nop 0\n\t" \
  "v_add_f32 v94, 1.0, v94\n\t" \
  "v_rcp_f32 v95, v94\n\t" \
  "s_nop 0\n\t" \
  "v_fma_f32 v99, -2.0, v95, v96\n\t" \
  "s_and_saveexec_b64 s[20:21], s[22:23]\n\t" \
  "ds_write_b32 " WR ", v99\n\t" \
  "global_store_dword v[100:101], v99, off offset:-2048\n\t" \
  "s_mov_b64 exec, s[20:21]\n\t" \
  "v_mov_b32 " MD ", " MS "\n\t" \
  "v_add_co_u32 v100, vcc, 0x400, v100\n\t" \
  "v_addc_co_u32 v101, vcc, v101, 0, vcc\n\t" \
  "s_waitcnt lgkmcnt(0)\n\t" \
  "s_barrier\n\t"

__global__ __attribute__((amdgpu_flat_work_group_size(512, 512)))
void rnn_scan_kernel(const float* __restrict__ Wh,
                     float* __restrict__ out) {
    const int tid = threadIdx.x;
    const int o   = tid & 15;
    const int pc  = tid >> 4;
    const int b   = blockIdx.x;

    // buf0 @ base+0, buf1 @ base+2048; padded slot(f)=f+4*(f>>4)
    __shared__ __align__(16) float hraw[1024];
    hraw[tid] = 0.0f; hraw[tid + 512] = 0.0f;
    __syncthreads();

    unsigned lbase = (unsigned)(unsigned long long)
                     (__attribute__((address_space(3))) char*)hraw;
    const int col  = pc + 32 * (o & 7);
    const int slot = col + 4 * (col >> 4);
    const unsigned rda = lbase + 80u * (unsigned)o;           // read buf0
    const unsigned rdb = rda + 2048u;                         // read buf1
    const unsigned wra = lbase + 2048u + 4u * (unsigned)slot; // write buf1
    const unsigned wrb = wra - 2048u;                         // write buf0

    const float* xa = out + ((size_t)b * SEQ + 2) * HIDDEN + col; // ptr@row2
    const unsigned xlo = (unsigned)(size_t)xa;
    const unsigned xhi = (unsigned)((size_t)xa >> 32);

    const float* wp0 = Wh + (size_t)(pc +   0) * HIDDEN + 16 * o;
    const float* wp1 = Wh + (size_t)(pc +  32) * HIDDEN + 16 * o;
    const float* wp2 = Wh + (size_t)(pc +  64) * HIDDEN + 16 * o;
    const float* wp3 = Wh + (size_t)(pc +  96) * HIDDEN + 16 * o;
    const float* wp4 = Wh + (size_t)(pc + 128) * HIDDEN + 16 * o;
    const float* wp5 = Wh + (size_t)(pc + 160) * HIDDEN + 16 * o;
    const float* wp6 = Wh + (size_t)(pc + 192) * HIDDEN + 16 * o;
    const float* wp7 = Wh + (size_t)(pc + 224) * HIDDEN + 16 * o;

    asm volatile(
        // ---- prologue: weights -> v[128:255] (16 consecutive floats each),
        // xp regs, lane masks ----
        "v_mov_b32 v100, %[xlo]\n\t"
        "v_mov_b32 v101, %[xhi]\n\t"
        "v_mov_b32 v96, 1.0\n\t"
        "global_load_dwordx4 v[128:131], %[wp0], off\n\t"
        "global_load_dwordx4 v[132:135], %[wp0], off offset:16\n\t"
        "global_load_dwordx4 v[136:139], %[wp0], off offset:32\n\t"
        "global_load_dwordx4 v[140:143], %[wp0], off offset:48\n\t"
        "global_load_dwordx4 v[144:147], %[wp1], off\n\t"
        "global_load_dwordx4 v[148:151], %[wp1], off offset:16\n\t"
        "global_load_dwordx4 v[152:155], %[wp1], off offset:32\n\t"
        "global_load_dwordx4 v[156:159], %[wp1], off offset:48\n\t"
        "global_load_dwordx4 v[160:163], %[wp2], off\n\t"
        "global_load_dwordx4 v[164:167], %[wp2], off offset:16\n\t"
        "global_load_dwordx4 v[168:171], %[wp2], off offset:32\n\t"
        "global_load_dwordx4 v[172:175], %[wp2], off offset:48\n\t"
        "global_load_dwordx4 v[176:179], %[wp3], off\n\t"
        "global_load_dwordx4 v[180:183], %[wp3], off offset:16\n\t"
        "global_load_dwordx4 v[184:187], %[wp3], off offset:32\n\t"
        "global_load_dwordx4 v[188:191], %[wp3], off offset:48\n\t"
        "global_load_dwordx4 v[192:195], %[wp4], off\n\t"
        "global_load_dwordx4 v[196:199], %[wp4], off offset:16\n\t"
        "global_load_dwordx4 v[200:203], %[wp4], off offset:32\n\t"
        "global_load_dwordx4 v[204:207], %[wp4], off offset:48\n\t"
        "global_load_dwordx4 v[208:211], %[wp5], off\n\t"
        "global_load_dwordx4 v[212:215], %[wp5], off offset:16\n\t"
        "global_load_dwordx4 v[216:219], %[wp5], off offset:32\n\t"
        "global_load_dwordx4 v[220:223], %[wp5], off offset:48\n\t"
        "global_load_dwordx4 v[224:227], %[wp6], off\n\t"
        "global_load_dwordx4 v[228:231], %[wp6], off offset:16\n\t"
        "global_load_dwordx4 v[232:235], %[wp6], off offset:32\n\t"
        "global_load_dwordx4 v[236:239], %[wp6], off offset:48\n\t"
        "global_load_dwordx4 v[240:243], %[wp7], off\n\t"
        "global_load_dwordx4 v[244:247], %[wp7], off offset:16\n\t"
        "global_load_dwordx4 v[248:251], %[wp7], off offset:32\n\t"
        "global_load_dwordx4 v[252:255], %[wp7], off offset:48\n\t"
        "global_load_dword v97,  v[100:101], off offset:-2048\n\t"  // row 0
        "global_load_dword v103, v[100:101], off offset:-1024\n\t"  // row 1
        "v_and_b32 v88, 1, %[vo]\n\t"
        "v_cmp_eq_u32 s[24:25], 1, v88\n\t"
        "v_and_b32 v88, 2, %[vo]\n\t"
        "v_cmp_eq_u32 s[26:27], 2, v88\n\t"
        "v_and_b32 v88, 4, %[vo]\n\t"
        "v_cmp_eq_u32 s[28:29], 4, v88\n\t"
        "v_cmp_gt_u32 s[22:23], 8, %[vo]\n\t"
        "s_movk_i32 s30, 0x400\n\t"
        "s_waitcnt vmcnt(0)\n\t"
        // ---- main loop: 1024 iterations x 2 steps; ptr = row t+2 at half A
        "RNN%=:\n\t"
        // half A top: prefetch row t+2 -> v102 (last iter: dummy row 2047)
        "s_cmp_eq_u32 s30, 1\n\t"
        "s_cbranch_scc1 LDA%=\n\t"
        "global_load_dword v102, v[100:101], off\n\t"
        "s_branch LCA%=\n\t"
        "LDA%=:\n\t"
        "global_load_dword v102, v[100:101], off offset:-1024\n\t"
        "LCA%=:\n\t"
        MAC_ASM("%[rda]")
        RED_ASM
        FIN_ASM("%[wra]", "v97", "v98", "v103")
        // half B top: prefetch row t+3 -> v103 (last iter: dummy row 2047)
        "s_cmp_eq_u32 s30, 1\n\t"
        "s_cbranch_scc1 LDB%=\n\t"
        "global_load_dword v103, v[100:101], off\n\t"
        "s_branch LCB%=\n\t"
        "LDB%=:\n\t"
        "global_load_dword v103, v[100:101], off offset:-2048\n\t"
        "LCB%=:\n\t"
        MAC_ASM("%[rdb]")
        RED_ASM
        FIN_ASM("%[wrb]", "v98", "v97", "v102")
        "s_sub_u32 s30, s30, 1\n\t"
        "s_cmp_lg_u32 s30, 0\n\t"
        "s_cbranch_scc1 RNN%=\n\t"
        "s_waitcnt vmcnt(0) lgkmcnt(0)\n\t"
        :
        : [wp0] "v"(wp0), [wp1] "v"(wp1), [wp2] "v"(wp2), [wp3] "v"(wp3),
          [wp4] "v"(wp4), [wp5] "v"(wp5), [wp6] "v"(wp6), [wp7] "v"(wp7),
          [xlo] "v"(xlo), [xhi] "v"(xhi),
          [rda] "v"(rda), [rdb] "v"(rdb), [wra] "v"(wra), [wrb] "v"(wrb),
          [vo]  "v"(o)
        : "memory", "vcc", "scc",
          "s20","s21","s22","s23","s24","s25","s26","s27","s28","s29","s30",
          "v48","v49","v50","v51","v52","v53","v54","v55",
          "v56","v57","v58","v59","v60","v61","v62","v63",
          "v64","v65","v66","v67","v68","v69","v70","v71",
          "v72","v73","v74","v75","v76","v77","v78","v79",
          "v80","v81","v82","v83","v84","v85","v86","v87",
          "v88","v89","v90","v91","v92","v93","v94","v95",
          "v96","v97","v98","v99","v100","v101","v102","v103",
          "v104","v105","v106","v107","v108","v109","v110","v111",
          "v112","v113","v114","v115","v116","v117","v118","v119",
          "v120","v121","v122","v123","v124","v125","v126","v127",
          "v128","v129","v130","v131","v132","v133","v134","v135",
          "v136","v137","v138","v139","v140","v141","v142","v143",
          "v144","v145","v146","v147","v148","v149","v150","v151",
          "v152","v153","v154","v155","v156","v157","v158","v159",
          "v160","v161","v162","v163","v164","v165","v166","v167",
          "v168","v169","v170","v171","v172","v173","v174","v175",
          "v176","v177","v178","v179","v180","v181","v182","v183",
          "v184","v185","v186","v187","v188","v189","v190","v191",
          "v192","v193","v194","v195","v196","v197","v198","v199",
          "v200","v201","v202","v203","v204","v205","v206","v207",
          "v208","v209","v210","v211","v212","v213","v214","v215",
          "v216","v217","v218","v219","v220","v221","v222","v223",
          "v224","v225","v226","v227","v228","v229","v230","v231",
          "v232","v233","v234","v235","v236","v237","v238","v239",
          "v240","v241","v242","v243","v244","v245","v246","v247",
          "v248","v249","v250","v251","v252","v253","v254","v255");
}

extern "C" void kernel_launch(void* const* d_in, const int* in_sizes, int n_in,
                              void* d_out, int out_size, void* d_ws, size_t ws_size,
                              hipStream_t stream) {
    const int*   x     = (const int*)d_in[0];
    const float* embed = (const float*)d_in[1];
    const float* Wx    = (const float*)d_in[2];
    const float* Wxb   = (const float*)d_in[3];
    const float* Wh    = (const float*)d_in[4];
    float* out = (float*)d_out;

    const int nrows = BATCH * SEQ;                  // 131072, 32 rows/block
    xpre_kernel<<<nrows / 32, 256, 0, stream>>>(x, embed, Wx, Wxb, out);

    rnn_scan_kernel<<<BATCH, 512, 0, stream>>>(Wh, out);
}

// Round 21
// 1371.834 us; speedup vs baseline: 1.4477x; 1.4477x over previous
//
#include <hip/hip_runtime.h>
#include <hip/hip_bf16.h>

#define HIDDEN 256
#define BATCH  64
#define SEQ    2048

// ---------------------------------------------------------------------------
// Phase 1: x_pre[row,h] = bias[h] + sum_d embed[x[row],d] * Wx[h,d]
// 32 rows/block, 256 thr, 16 rows x 2 cols per thread; e staged in LDS,
// broadcast b128 reads. MEASURED OPTIMUM of the tile space (~250us):
// (8rx4c) = 500-865us (W re-read amplification: rows/thread halves -> W
// VMEM doubles), (32rx1c scalarized-e) = 580us (SMEM serialization).
// ---------------------------------------------------------------------------
__global__ __launch_bounds__(256, 4)
void xpre_kernel(const int* __restrict__ x,
                 const float* __restrict__ embed,
                 const float* __restrict__ Wx,
                 const float* __restrict__ bias,
                 float* __restrict__ out) {
    const int tid = threadIdx.x;
    const int hh  = tid >> 7;
    const int j2  = tid & 127;
    const long row0 = (long)blockIdx.x * 32;

    __shared__ int toks[32];
    __shared__ __align__(16) float e[32][HIDDEN];

    if (tid < 32) toks[tid] = x[row0 + tid];
    __syncthreads();

    #pragma unroll
    for (int r = 0; r < 32; ++r) {
        e[r][tid] = embed[(long)toks[r] * HIDDEN + tid];
    }
    __syncthreads();

    float acc0[16], acc1[16];
    const float b0 = bias[j2];
    const float b1 = bias[j2 + 128];
    #pragma unroll
    for (int r = 0; r < 16; ++r) { acc0[r] = b0; acc1[r] = b1; }

    const float* wrow0 = Wx + (size_t)j2 * HIDDEN;
    const float* wrow1 = Wx + (size_t)(j2 + 128) * HIDDEN;

    #pragma unroll 2
    for (int d0 = 0; d0 < HIDDEN; d0 += 4) {
        const float4 w0 = *(const float4*)(wrow0 + d0);
        const float4 w1 = *(const float4*)(wrow1 + d0);
        #pragma unroll
        for (int r = 0; r < 16; ++r) {
            const float4 ev = *(const float4*)&e[(hh << 4) + r][d0];
            float a = acc0[r];
            a = fmaf(w0.x, ev.x, a); a = fmaf(w0.y, ev.y, a);
            a = fmaf(w0.z, ev.z, a); a = fmaf(w0.w, ev.w, a);
            acc0[r] = a;
            float c = acc1[r];
            c = fmaf(w1.x, ev.x, c); c = fmaf(w1.y, ev.y, c);
            c = fmaf(w1.z, ev.z, c); c = fmaf(w1.w, ev.w, c);
            acc1[r] = c;
        }
    }

    #pragma unroll
    for (int r = 0; r < 16; ++r) {
        const long orow = (row0 + (hh << 4) + r) * HIDDEN;
        out[orow + j2]       = acc0[r];
        out[orow + j2 + 128] = acc1[r];
    }
}

// ---------------------------------------------------------------------------
// Phase 2: whole-loop-in-asm F32 scan — exact R14 configuration (best
// measured: 1120us, reproduced 3x). 512 thr (2 waves/EU), thread (o=tid&15,
// pc=tid>>4): 8 cols {pc+32k}, h-slice h[16o..16o+15]; weights hand-pinned
// v[128:255] (the 9-round allocator fight ends by hand allocation);
// counted lgkmcnt(3/2/1/0) MAC interleave; DPP merge-reduce; 2-deep x_pre
// prefetch with vmcnt(2); ds_write before global_store; lgkm-only barrier.
// ---------------------------------------------------------------------------

#define MAC_ASM(RD) \
  "ds_read_b128 v[48:51], " RD "\n\t" \
  "ds_read_b128 v[52:55], " RD " offset:16\n\t" \
  "ds_read_b128 v[56:59], " RD " offset:32\n\t" \
  "ds_read_b128 v[60:63], " RD " offset:48\n\t" \
  "s_waitcnt lgkmcnt(3)\n\t" \
  "v_pk_mul_f32 v[64:65], v[128:129], v[48:49]\n\t" \
  "v_pk_mul_f32 v[66:67], v[144:145], v[48:49]\n\t" \
  "v_pk_mul_f32 v[68:69], v[160:161], v[48:49]\n\t" \
  "v_pk_mul_f32 v[70:71], v[176:177], v[48:49]\n\t" \
  "v_pk_mul_f32 v[72:73], v[192:193], v[48:49]\n\t" \
  "v_pk_mul_f32 v[74:75], v[208:209], v[48:49]\n\t" \
  "v_pk_mul_f32 v[76:77], v[224:225], v[48:49]\n\t" \
  "v_pk_mul_f32 v[78:79], v[240:241], v[48:49]\n\t" \
  "v_pk_fma_f32 v[64:65], v[130:131], v[50:51], v[64:65]\n\t" \
  "v_pk_fma_f32 v[66:67], v[146:147], v[50:51], v[66:67]\n\t" \
  "v_pk_fma_f32 v[68:69], v[162:163], v[50:51], v[68:69]\n\t" \
  "v_pk_fma_f32 v[70:71], v[178:179], v[50:51], v[70:71]\n\t" \
  "v_pk_fma_f32 v[72:73], v[194:195], v[50:51], v[72:73]\n\t" \
  "v_pk_fma_f32 v[74:75], v[210:211], v[50:51], v[74:75]\n\t" \
  "v_pk_fma_f32 v[76:77], v[226:227], v[50:51], v[76:77]\n\t" \
  "v_pk_fma_f32 v[78:79], v[242:243], v[50:51], v[78:79]\n\t" \
  "s_waitcnt lgkmcnt(2)\n\t" \
  "v_pk_fma_f32 v[64:65], v[132:133], v[52:53], v[64:65]\n\t" \
  "v_pk_fma_f32 v[66:67], v[148:149], v[52:53], v[66:67]\n\t" \
  "v_pk_fma_f32 v[68:69], v[164:165], v[52:53], v[68:69]\n\t" \
  "v_pk_fma_f32 v[70:71], v[180:181], v[52:53], v[70:71]\n\t" \
  "v_pk_fma_f32 v[72:73], v[196:197], v[52:53], v[72:73]\n\t" \
  "v_pk_fma_f32 v[74:75], v[212:213], v[52:53], v[74:75]\n\t" \
  "v_pk_fma_f32 v[76:77], v[228:229], v[52:53], v[76:77]\n\t" \
  "v_pk_fma_f32 v[78:79], v[244:245], v[52:53], v[78:79]\n\t" \
  "v_pk_fma_f32 v[64:65], v[134:135], v[54:55], v[64:65]\n\t" \
  "v_pk_fma_f32 v[66:67], v[150:151], v[54:55], v[66:67]\n\t" \
  "v_pk_fma_f32 v[68:69], v[166:167], v[54:55], v[68:69]\n\t" \
  "v_pk_fma_f32 v[70:71], v[182:183], v[54:55], v[70:71]\n\t" \
  "v_pk_fma_f32 v[72:73], v[198:199], v[54:55], v[72:73]\n\t" \
  "v_pk_fma_f32 v[74:75], v[214:215], v[54:55], v[74:75]\n\t" \
  "v_pk_fma_f32 v[76:77], v[230:231], v[54:55], v[76:77]\n\t" \
  "v_pk_fma_f32 v[78:79], v[246:247], v[54:55], v[78:79]\n\t" \
  "s_waitcnt lgkmcnt(1)\n\t" \
  "v_pk_fma_f32 v[64:65], v[136:137], v[56:57], v[64:65]\n\t" \
  "v_pk_fma_f32 v[66:67], v[152:153], v[56:57], v[66:67]\n\t" \
  "v_pk_fma_f32 v[68:69], v[168:169], v[56:57], v[68:69]\n\t" \
  "v_pk_fma_f32 v[70:71], v[184:185], v[56:57], v[70:71]\n\t" \
  "v_pk_fma_f32 v[72:73], v[200:201], v[56:57], v[72:73]\n\t" \
  "v_pk_fma_f32 v[74:75], v[216:217], v[56:57], v[74:75]\n\t" \
  "v_pk_fma_f32 v[76:77], v[232:233], v[56:57], v[76:77]\n\t" \
  "v_pk_fma_f32 v[78:79], v[248:249], v[56:57], v[78:79]\n\t" \
  "v_pk_fma_f32 v[64:65], v[138:139], v[58:59], v[64:65]\n\t" \
  "v_pk_fma_f32 v[66:67], v[154:155], v[58:59], v[66:67]\n\t" \
  "v_pk_fma_f32 v[68:69], v[170:171], v[58:59], v[68:69]\n\t" \
  "v_pk_fma_f32 v[70:71], v[186:187], v[58:59], v[70:71]\n\t" \
  "v_pk_fma_f32 v[72:73], v[202:203], v[58:59], v[72:73]\n\t" \
  "v_pk_fma_f32 v[74:75], v[218:219], v[58:59], v[74:75]\n\t" \
  "v_pk_fma_f32 v[76:77], v[234:235], v[58:59], v[76:77]\n\t" \
  "v_pk_fma_f32 v[78:79], v[250:251], v[58:59], v[78:79]\n\t" \
  "s_waitcnt lgkmcnt(0)\n\t" \
  "v_pk_fma_f32 v[64:65], v[140:141], v[60:61], v[64:65]\n\t" \
  "v_pk_fma_f32 v[66:67], v[156:157], v[60:61], v[66:67]\n\t" \
  "v_pk_fma_f32 v[68:69], v[172:173], v[60:61], v[68:69]\n\t" \
  "v_pk_fma_f32 v[70:71], v[188:189], v[60:61], v[70:71]\n\t" \
  "v_pk_fma_f32 v[72:73], v[204:205], v[60:61], v[72:73]\n\t" \
  "v_pk_fma_f32 v[74:75], v[220:221], v[60:61], v[74:75]\n\t" \
  "v_pk_fma_f32 v[76:77], v[236:237], v[60:61], v[76:77]\n\t" \
  "v_pk_fma_f32 v[78:79], v[252:253], v[60:61], v[78:79]\n\t" \
  "v_pk_fma_f32 v[64:65], v[142:143], v[62:63], v[64:65]\n\t" \
  "v_pk_fma_f32 v[66:67], v[158:159], v[62:63], v[66:67]\n\t" \
  "v_pk_fma_f32 v[68:69], v[174:175], v[62:63], v[68:69]\n\t" \
  "v_pk_fma_f32 v[70:71], v[190:191], v[62:63], v[70:71]\n\t" \
  "v_pk_fma_f32 v[72:73], v[206:207], v[62:63], v[72:73]\n\t" \
  "v_pk_fma_f32 v[74:75], v[222:223], v[62:63], v[74:75]\n\t" \
  "v_pk_fma_f32 v[76:77], v[238:239], v[62:63], v[76:77]\n\t" \
  "v_pk_fma_f32 v[78:79], v[254:255], v[62:63], v[78:79]\n\t" \
  "v_add_f32 v80, v64, v65\n\t" \
  "v_add_f32 v81, v66, v67\n\t" \
  "v_add_f32 v82, v68, v69\n\t" \
  "v_add_f32 v83, v70, v71\n\t" \
  "v_add_f32 v84, v72, v73\n\t" \
  "v_add_f32 v85, v74, v75\n\t" \
  "v_add_f32 v86, v76, v77\n\t" \
  "v_add_f32 v87, v78, v79\n\t"

// merge-reduce over the 16 o-lanes; lane o ends with total for col pc+32*(o&7)
#define RED_ASM \
  "v_add_f32_dpp v80, v80, v80 row_ror:8 row_mask:0xf bank_mask:0xf\n\t" \
  "v_add_f32_dpp v81, v81, v81 row_ror:8 row_mask:0xf bank_mask:0xf\n\t" \
  "v_add_f32_dpp v82, v82, v82 row_ror:8 row_mask:0xf bank_mask:0xf\n\t" \
  "v_add_f32_dpp v83, v83, v83 row_ror:8 row_mask:0xf bank_mask:0xf\n\t" \
  "v_add_f32_dpp v84, v84, v84 row_ror:8 row_mask:0xf bank_mask:0xf\n\t" \
  "v_add_f32_dpp v85, v85, v85 row_ror:8 row_mask:0xf bank_mask:0xf\n\t" \
  "v_add_f32_dpp v86, v86, v86 row_ror:8 row_mask:0xf bank_mask:0xf\n\t" \
  "v_add_f32_dpp v87, v87, v87 row_ror:8 row_mask:0xf bank_mask:0xf\n\t" \
  "v_cndmask_b32 v88, v81, v80, s[24:25]\n\t" \
  "v_cndmask_b32 v89, v83, v82, s[24:25]\n\t" \
  "v_cndmask_b32 v90, v85, v84, s[24:25]\n\t" \
  "v_cndmask_b32 v91, v87, v86, s[24:25]\n\t" \
  "v_cndmask_b32 v80, v80, v81, s[24:25]\n\t" \
  "v_cndmask_b32 v82, v82, v83, s[24:25]\n\t" \
  "v_cndmask_b32 v84, v84, v85, s[24:25]\n\t" \
  "v_cndmask_b32 v86, v86, v87, s[24:25]\n\t" \
  "v_add_f32_dpp v80, v88, v80 quad_perm:[1,0,3,2] row_mask:0xf bank_mask:0xf\n\t" \
  "v_add_f32_dpp v82, v89, v82 quad_perm:[1,0,3,2] row_mask:0xf bank_mask:0xf\n\t" \
  "v_add_f32_dpp v84, v90, v84 quad_perm:[1,0,3,2] row_mask:0xf bank_mask:0xf\n\t" \
  "v_add_f32_dpp v86, v91, v86 quad_perm:[1,0,3,2] row_mask:0xf bank_mask:0xf\n\t" \
  "v_cndmask_b32 v88, v82, v80, s[26:27]\n\t" \
  "v_cndmask_b32 v89, v86, v84, s[26:27]\n\t" \
  "v_cndmask_b32 v80, v80, v82, s[26:27]\n\t" \
  "v_cndmask_b32 v84, v84, v86, s[26:27]\n\t" \
  "s_nop 1\n\t" \
  "v_add_f32_dpp v80, v88, v80 quad_perm:[2,3,0,1] row_mask:0xf bank_mask:0xf\n\t" \
  "v_add_f32_dpp v84, v89, v84 quad_perm:[2,3,0,1] row_mask:0xf bank_mask:0xf\n\t" \
  "v_cndmask_b32 v88, v84, v80, s[28:29]\n\t" \
  "v_cndmask_b32 v80, v80, v84, s[28:29]\n\t" \
  "s_nop 1\n\t" \
  "v_add_f32_dpp v80, v88, v80 row_ror:4 row_mask:0xf bank_mask:0xf\n\t"

// finish: counted vmcnt wait, xp add, tanh, ds_write FIRST then global store,
// prefetch-reg rotate, pointer advance, lgkmcnt-only barrier.
#define FIN_ASM(WR, XP, MD, MS) \
  "s_waitcnt vmcnt(2)\n\t" \
  "v_add_f32 v99, v80, " XP "\n\t" \
  "v_mul_f32 v93, 0x4038AA3B, v99\n\t" \
  "v_exp_f32 v94, v93\n\t" \
  "s_nop 0\n\t" \
  "v_add_f32 v94, 1.0, v94\n\t" \
  "v_rcp_f32 v95, v94\n\t" \
  "s_nop 0\n\t" \
  "v_fma_f32 v99, -2.0, v95, v96\n\t" \
  "s_and_saveexec_b64 s[20:21], s[22:23]\n\t" \
  "ds_write_b32 " WR ", v99\n\t" \
  "global_store_dword v[100:101], v99, off offset:-2048\n\t" \
  "s_mov_b64 exec, s[20:21]\n\t" \
  "v_mov_b32 " MD ", " MS "\n\t" \
  "v_add_co_u32 v100, vcc, 0x400, v100\n\t" \
  "v_addc_co_u32 v101, vcc, v101, 0, vcc\n\t" \
  "s_waitcnt lgkmcnt(0)\n\t" \
  "s_barrier\n\t"

__global__ __attribute__((amdgpu_flat_work_group_size(512, 512)))
void rnn_scan_kernel(const float* __restrict__ Wh,
                     float* __restrict__ out) {
    const int tid = threadIdx.x;
    const int o   = tid & 15;
    const int pc  = tid >> 4;
    const int b   = blockIdx.x;

    // buf0 @ base+0, buf1 @ base+2048; padded slot(f)=f+4*(f>>4)
    __shared__ __align__(16) float hraw[1024];
    hraw[tid] = 0.0f; hraw[tid + 512] = 0.0f;
    __syncthreads();

    unsigned lbase = (unsigned)(unsigned long long)
                     (__attribute__((address_space(3))) char*)hraw;
    const int col  = pc + 32 * (o & 7);
    const int slot = col + 4 * (col >> 4);
    const unsigned rda = lbase + 80u * (unsigned)o;           // read buf0
    const unsigned rdb = rda + 2048u;                         // read buf1
    const unsigned wra = lbase + 2048u + 4u * (unsigned)slot; // write buf1
    const unsigned wrb = wra - 2048u;                         // write buf0

    const float* xa = out + ((size_t)b * SEQ + 2) * HIDDEN + col; // ptr@row2
    const unsigned xlo = (unsigned)(size_t)xa;
    const unsigned xhi = (unsigned)((size_t)xa >> 32);

    const float* wp0 = Wh + (size_t)(pc +   0) * HIDDEN + 16 * o;
    const float* wp1 = Wh + (size_t)(pc +  32) * HIDDEN + 16 * o;
    const float* wp2 = Wh + (size_t)(pc +  64) * HIDDEN + 16 * o;
    const float* wp3 = Wh + (size_t)(pc +  96) * HIDDEN + 16 * o;
    const float* wp4 = Wh + (size_t)(pc + 128) * HIDDEN + 16 * o;
    const float* wp5 = Wh + (size_t)(pc + 160) * HIDDEN + 16 * o;
    const float* wp6 = Wh + (size_t)(pc + 192) * HIDDEN + 16 * o;
    const float* wp7 = Wh + (size_t)(pc + 224) * HIDDEN + 16 * o;

    asm volatile(
        // ---- prologue: weights -> v[128:255] (16 consecutive floats each),
        // xp regs, lane masks ----
        "v_mov_b32 v100, %[xlo]\n\t"
        "v_mov_b32 v101, %[xhi]\n\t"
        "v_mov_b32 v96, 1.0\n\t"
        "global_load_dwordx4 v[128:131], %[wp0], off\n\t"
        "global_load_dwordx4 v[132:135], %[wp0], off offset:16\n\t"
        "global_load_dwordx4 v[136:139], %[wp0], off offset:32\n\t"
        "global_load_dwordx4 v[140:143], %[wp0], off offset:48\n\t"
        "global_load_dwordx4 v[144:147], %[wp1], off\n\t"
        "global_load_dwordx4 v[148:151], %[wp1], off offset:16\n\t"
        "global_load_dwordx4 v[152:155], %[wp1], off offset:32\n\t"
        "global_load_dwordx4 v[156:159], %[wp1], off offset:48\n\t"
        "global_load_dwordx4 v[160:163], %[wp2], off\n\t"
        "global_load_dwordx4 v[164:167], %[wp2], off offset:16\n\t"
        "global_load_dwordx4 v[168:171], %[wp2], off offset:32\n\t"
        "global_load_dwordx4 v[172:175], %[wp2], off offset:48\n\t"
        "global_load_dwordx4 v[176:179], %[wp3], off\n\t"
        "global_load_dwordx4 v[180:183], %[wp3], off offset:16\n\t"
        "global_load_dwordx4 v[184:187], %[wp3], off offset:32\n\t"
        "global_load_dwordx4 v[188:191], %[wp3], off offset:48\n\t"
        "global_load_dwordx4 v[192:195], %[wp4], off\n\t"
        "global_load_dwordx4 v[196:199], %[wp4], off offset:16\n\t"
        "global_load_dwordx4 v[200:203], %[wp4], off offset:32\n\t"
        "global_load_dwordx4 v[204:207], %[wp4], off offset:48\n\t"
        "global_load_dwordx4 v[208:211], %[wp5], off\n\t"
        "global_load_dwordx4 v[212:215], %[wp5], off offset:16\n\t"
        "global_load_dwordx4 v[216:219], %[wp5], off offset:32\n\t"
        "global_load_dwordx4 v[220:223], %[wp5], off offset:48\n\t"
        "global_load_dwordx4 v[224:227], %[wp6], off\n\t"
        "global_load_dwordx4 v[228:231], %[wp6], off offset:16\n\t"
        "global_load_dwordx4 v[232:235], %[wp6], off offset:32\n\t"
        "global_load_dwordx4 v[236:239], %[wp6], off offset:48\n\t"
        "global_load_dwordx4 v[240:243], %[wp7], off\n\t"
        "global_load_dwordx4 v[244:247], %[wp7], off offset:16\n\t"
        "global_load_dwordx4 v[248:251], %[wp7], off offset:32\n\t"
        "global_load_dwordx4 v[252:255], %[wp7], off offset:48\n\t"
        "global_load_dword v97,  v[100:101], off offset:-2048\n\t"  // row 0
        "global_load_dword v103, v[100:101], off offset:-1024\n\t"  // row 1
        "v_and_b32 v88, 1, %[vo]\n\t"
        "v_cmp_eq_u32 s[24:25], 1, v88\n\t"
        "v_and_b32 v88, 2, %[vo]\n\t"
        "v_cmp_eq_u32 s[26:27], 2, v88\n\t"
        "v_and_b32 v88, 4, %[vo]\n\t"
        "v_cmp_eq_u32 s[28:29], 4, v88\n\t"
        "v_cmp_gt_u32 s[22:23], 8, %[vo]\n\t"
        "s_movk_i32 s30, 0x400\n\t"
        "s_waitcnt vmcnt(0)\n\t"
        // ---- main loop: 1024 iterations x 2 steps; ptr = row t+2 at half A
        "RNN%=:\n\t"
        // half A top: prefetch row t+2 -> v102 (last iter: dummy row 2047)
        "s_cmp_eq_u32 s30, 1\n\t"
        "s_cbranch_scc1 LDA%=\n\t"
        "global_load_dword v102, v[100:101], off\n\t"
        "s_branch LCA%=\n\t"
        "LDA%=:\n\t"
        "global_load_dword v102, v[100:101], off offset:-1024\n\t"
        "LCA%=:\n\t"
        MAC_ASM("%[rda]")
        RED_ASM
        FIN_ASM("%[wra]", "v97", "v98", "v103")
        // half B top: prefetch row t+3 -> v103 (last iter: dummy row 2047)
        "s_cmp_eq_u32 s30, 1\n\t"
        "s_cbranch_scc1 LDB%=\n\t"
        "global_load_dword v103, v[100:101], off\n\t"
        "s_branch LCB%=\n\t"
        "LDB%=:\n\t"
        "global_load_dword v103, v[100:101], off offset:-2048\n\t"
        "LCB%=:\n\t"
        MAC_ASM("%[rdb]")
        RED_ASM
        FIN_ASM("%[wrb]", "v98", "v97", "v102")
        "s_sub_u32 s30, s30, 1\n\t"
        "s_cmp_lg_u32 s30, 0\n\t"
        "s_cbranch_scc1 RNN%=\n\t"
        "s_waitcnt vmcnt(0) lgkmcnt(0)\n\t"
        :
        : [wp0] "v"(wp0), [wp1] "v"(wp1), [wp2] "v"(wp2), [wp3] "v"(wp3),
          [wp4] "v"(wp4), [wp5] "v"(wp5), [wp6] "v"(wp6), [wp7] "v"(wp7),
          [xlo] "v"(xlo), [xhi] "v"(xhi),
          [rda] "v"(rda), [rdb] "v"(rdb), [wra] "v"(wra), [wrb] "v"(wrb),
          [vo]  "v"(o)
        : "memory", "vcc", "scc",
          "s20","s21","s22","s23","s24","s25","s26","s27","s28","s29","s30",
          "v48","v49","v50","v51","v52","v53","v54","v55",
          "v56","v57","v58","v59","v60","v61","v62","v63",
          "v64","v65","v66","v67","v68","v69","v70","v71",
          "v72","v73","v74","v75","v76","v77","v78","v79",
          "v80","v81","v82","v83","v84","v85","v86","v87",
          "v88","v89","v90","v91","v92","v93","v94","v95",
          "v96","v97","v98","v99","v100","v101","v102","v103",
          "v104","v105","v106","v107","v108","v109","v110","v111",
          "v112","v113","v114","v115","v116","v117","v118","v119",
          "v120","v121","v122","v123","v124","v125","v126","v127",
          "v128","v129","v130","v131","v132","v133","v134","v135",
          "v136","v137","v138","v139","v140","v141","v142","v143",
          "v144","v145","v146","v147","v148","v149","v150","v151",
          "v152","v153","v154","v155","v156","v157","v158","v159",
          "v160","v161","v162","v163","v164","v165","v166","v167",
          "v168","v169","v170","v171","v172","v173","v174","v175",
          "v176","v177","v178","v179","v180","v181","v182","v183",
          "v184","v185","v186","v187","v188","v189","v190","v191",
          "v192","v193","v194","v195","v196","v197","v198","v199",
          "v200","v201","v202","v203","v204","v205","v206","v207",
          "v208","v209","v210","v211","v212","v213","v214","v215",
          "v216","v217","v218","v219","v220","v221","v222","v223",
          "v224","v225","v226","v227","v228","v229","v230","v231",
          "v232","v233","v234","v235","v236","v237","v238","v239",
          "v240","v241","v242","v243","v244","v245","v246","v247",
          "v248","v249","v250","v251","v252","v253","v254","v255");
}

extern "C" void kernel_launch(void* const* d_in, const int* in_sizes, int n_in,
                              void* d_out, int out_size, void* d_ws, size_t ws_size,
                              hipStream_t stream) {
    const int*   x     = (const int*)d_in[0];
    const float* embed = (const float*)d_in[1];
    const float* Wx    = (const float*)d_in[2];
    const float* Wxb   = (const float*)d_in[3];
    const float* Wh    = (const float*)d_in[4];
    float* out = (float*)d_out;

    const int nrows = BATCH * SEQ;                  // 131072, 32 rows/block
    xpre_kernel<<<nrows / 32, 256, 0, stream>>>(x, embed, Wx, Wxb, out);

    rnn_scan_kernel<<<BATCH, 512, 0, stream>>>(Wh, out);
}